// Round 1
// baseline (56.388 us; speedup 1.0000x reference)
//
#include <hip/hip_runtime.h>

// HilbertFlatten: out[s] = x[hilbert_decode(s)] for a (256,256,256) f32 array.
// num_dims=3, num_bits=8 -> 24-bit Hilbert indices. Decode done per-thread,
// branchless, entirely in registers.

__global__ __launch_bounds__(256) void hilbert_gather_kernel(
    const float* __restrict__ x, float* __restrict__ out, unsigned n) {
    unsigned s = blockIdx.x * 256u + threadIdx.x;
    if (s >= n) return;

    // gray code of the 24-bit hilbert integer
    unsigned g = s ^ (s >> 1);

    // De-interleave: G[d] bit k = g bit (3k + 2 - d).  (bit-plane integers,
    // bit k of G[d] is coordinate-bit (7-k), i.e. G[d] packs the coordinate
    // directly once the undo-transform loop below fixes the bits.)
    unsigned G[3];
#pragma unroll
    for (int d = 0; d < 3; ++d) {
        unsigned v = (g >> (2 - d)) & 0x00249249u;   // bits 0,3,...,21
        v = (v ^ (v >> 2)) & 0x030C30C3u;            // -> pairs
        v = (v ^ (v >> 4)) & 0x0300F00Fu;            // -> nibbles
        v = (v ^ (v >> 8)) & 0x000000FFu;            // -> byte
        G[d] = v;
    }

    // Undo the hilbert encode transforms. Reference loop:
    //   for bit in 7..0: for dim in 2..0:
    //     mask = g[dim][bit]
    //     if mask: invert dim-0 bits below 'bit'
    //     else:    swap dim bits below 'bit' with dim-0 bits
    // bit=7 is a no-op (empty lower slice), so start at 6.
    // Integer bit mapping: coordinate-bit b <-> integer bit (7-b); "bits
    // below b" = low (7-bit) integer bits.
#pragma unroll
    for (int bit = 6; bit >= 0; --bit) {
        const unsigned low = (1u << (7 - bit)) - 1u;
#pragma unroll
        for (int dim = 2; dim >= 0; --dim) {
            unsigned m = (G[dim] >> (7 - bit)) & 1u;       // mask bit
            unsigned diff = (G[0] ^ G[dim]) & low;
            unsigned t = diff & (m - 1u);                  // swap amount if m==0
            G[0] ^= ((0u - m) & low) ^ t;                  // invert if m==1, else swap
            G[dim] ^= t;                                   // (dim==0: t==0, harmless)
        }
    }

    unsigned flat = (G[0] << 16) | (G[1] << 8) | G[2];
    out[s] = x[flat];
}

extern "C" void kernel_launch(void* const* d_in, const int* in_sizes, int n_in,
                              void* d_out, int out_size, void* d_ws, size_t ws_size,
                              hipStream_t stream) {
    const float* x = (const float*)d_in[0];
    float* out = (float*)d_out;
    unsigned n = (unsigned)out_size;           // 256*256*256 = 16777216
    unsigned blocks = (n + 255u) / 256u;
    hilbert_gather_kernel<<<blocks, 256, 0, stream>>>(x, out, n);
}

// Round 2
// 32.447 us; speedup vs baseline: 1.7379x; 1.7379x over previous
//
#include <hip/hip_runtime.h>

// HilbertFlatten: out[s] = x[hilbert_decode(s)] for (256,256,256) f32.
// Each thread decodes ONE base curve index (multiple of 8) and derives the
// 8 consecutive outputs via the affine bit-0 map (probe-channel trick):
// in the undo loop, masks come only from integer bits 1..7, every op is
// bitwise, so bit-0 (and any probe bit we enroll in `low`) evolves under a
// fixed flip/swap sequence = affine map over GF(2)^3. Probes in bits 8..11
// recover A (columns) and c at zero in-loop cost.

__global__ __launch_bounds__(256) void hilbert_gather8_kernel(
    const float* __restrict__ x, float* __restrict__ out, unsigned ngroups) {
    // XCD-chunked bijective swizzle (gridDim.x divisible by 8): each XCD
    // gets a contiguous curve segment -> neighbor cubes hit same L2.
    unsigned nb = blockIdx.x;
    unsigned cpx = gridDim.x >> 3;                 // blocks per XCD
    unsigned b = (nb & 7u) * cpx + (nb >> 3);
    unsigned gid = b * 256u + threadIdx.x;         // group id (8 elems each)
    if (gid >= ngroups) return;
    unsigned S = gid << 3;                         // base curve index

    unsigned g = S ^ (S >> 1);

    // De-interleave 24-bit gray -> three 8-bit bit-plane ints.
    unsigned G[3];
#pragma unroll
    for (int d = 0; d < 3; ++d) {
        unsigned v = (g >> (2 - d)) & 0x00249249u;
        v = (v ^ (v >> 2)) & 0x030C30C3u;
        v = (v ^ (v >> 4)) & 0x0300F00Fu;
        v = (v ^ (v >> 8)) & 0x000000FFu;
        G[d] = v;
    }
    // Probe channels (bits 8..11): init = e0,e1,e2 across (G0,G1,G2); the
    // zero-initialized bit-11 channel yields the affine constant c.
    G[0] |= 0x100u;   // channel 0: (1,0,0)
    G[1] |= 0x200u;   // channel 1: (0,1,0)
    G[2] |= 0x400u;   // channel 2: (0,0,1)

    // Undo the hilbert encode transforms; probes enrolled via |0x0F00.
#pragma unroll
    for (int bit = 6; bit >= 0; --bit) {
        const unsigned low = ((1u << (7 - bit)) - 1u) | 0x0F00u;
#pragma unroll
        for (int dim = 2; dim >= 0; --dim) {
            unsigned m = (G[dim] >> (7 - bit)) & 1u;
            unsigned diff = (G[0] ^ G[dim]) & low;
            unsigned t = diff & (m - 1u);          // swap amount if m==0
            G[0] ^= ((0u - m) & low) ^ t;          // invert if m==1, else swap
            G[dim] ^= t;
        }
    }

    // Per-offset init bit-0 triples as bytes over r=0..7:
    // v0(r)=r2^s3 -> 0xF0^s3m, v1(r)=r1^r2 -> 0x3C, v2(r)=r0^r1 -> 0x66.
    unsigned s3m = 0u - ((S >> 3) & 1u);
    unsigned V0 = (0xF0u ^ s3m) & 0xFFu;
    const unsigned V1 = 0x3Cu, V2 = 0x66u;

    // B[d] bit r = final coord-d bit0 for offset r = (A row d)·u_r ^ c_d.
    unsigned B[3];
#pragma unroll
    for (int d = 0; d < 3; ++d) {
        unsigned cd = 0u - ((G[d] >> 11) & 1u);            // -c_d mask
        unsigned a0 = (0u - ((G[d] >> 8) & 1u)) ^ cd;      // -A_d0 mask
        unsigned a1 = (0u - ((G[d] >> 9) & 1u)) ^ cd;
        unsigned a2 = (0u - ((G[d] >> 10) & 1u)) ^ cd;
        B[d] = ((a0 & V0) ^ (a1 & V1) ^ (a2 & V2) ^ cd) & 0xFFu;
    }

    unsigned baseflat = ((G[0] & 0xFEu) << 16) | ((G[1] & 0xFEu) << 8)
                      | (G[2] & 0xFEu);

    float out8[8];
#pragma unroll
    for (int r = 0; r < 8; ++r) {
        unsigned f0 = (B[0] >> r) & 1u;
        unsigned f1 = (B[1] >> r) & 1u;
        unsigned f2 = (B[2] >> r) & 1u;
        unsigned flat = baseflat | (f0 << 16) | (f1 << 8) | f2;
        out8[r] = x[flat];
    }
    float4* o4 = (float4*)(out + S);
    o4[0] = make_float4(out8[0], out8[1], out8[2], out8[3]);
    o4[1] = make_float4(out8[4], out8[5], out8[6], out8[7]);
}

extern "C" void kernel_launch(void* const* d_in, const int* in_sizes, int n_in,
                              void* d_out, int out_size, void* d_ws, size_t ws_size,
                              hipStream_t stream) {
    const float* x = (const float*)d_in[0];
    float* out = (float*)d_out;
    unsigned n = (unsigned)out_size;               // 16777216
    unsigned ngroups = n >> 3;                     // 2097152
    unsigned blocks = (ngroups + 255u) / 256u;     // 8192 (divisible by 8)
    hilbert_gather8_kernel<<<blocks, 256, 0, stream>>>(x, out, ngroups);
}

// Round 3
// 26.044 us; speedup vs baseline: 2.1651x; 1.2459x over previous
//
#include <hip/hip_runtime.h>

// HilbertFlatten: out[s] = x[hilbert_decode(s)] for (256,256,256) f32.
// One thread = one 2x2x2 cube = 8 consecutive curve points. Decode once with
// the probe-channel affine-bit0 trick; load the cube as 4x float2 (z-pairs
// are memory-contiguous); resolve curve order with a cndmask select tree.

__global__ __launch_bounds__(256) void hilbert_gather8v_kernel(
    const float* __restrict__ x, float* __restrict__ out, unsigned ngroups) {
    // XCD-chunked bijective swizzle (gridDim.x divisible by 8).
    unsigned nb = blockIdx.x;
    unsigned cpx = gridDim.x >> 3;
    unsigned b = (nb & 7u) * cpx + (nb >> 3);
    unsigned gid = b * 256u + threadIdx.x;
    if (gid >= ngroups) return;
    unsigned S = gid << 3;

    unsigned g = S ^ (S >> 1);

    // De-interleave 24-bit gray -> three 8-bit bit-plane ints.
    unsigned G[3];
#pragma unroll
    for (int d = 0; d < 3; ++d) {
        unsigned v = (g >> (2 - d)) & 0x00249249u;
        v = (v ^ (v >> 2)) & 0x030C30C3u;
        v = (v ^ (v >> 4)) & 0x0300F00Fu;
        v = (v ^ (v >> 8)) & 0x000000FFu;
        G[d] = v;
    }
    // Probe channels: bits 8..10 = identity basis, bit 11 = affine constant.
    G[0] |= 0x100u;
    G[1] |= 0x200u;
    G[2] |= 0x400u;

#pragma unroll
    for (int bit = 6; bit >= 0; --bit) {
        const unsigned low = ((1u << (7 - bit)) - 1u) | 0x0F00u;
#pragma unroll
        for (int dim = 2; dim >= 0; --dim) {
            unsigned m = (G[dim] >> (7 - bit)) & 1u;
            unsigned diff = (G[0] ^ G[dim]) & low;
            unsigned t = diff & (m - 1u);
            G[0] ^= ((0u - m) & low) ^ t;
            G[dim] ^= t;
        }
    }

    // Per-offset init bit0 triples over r=0..7 (bytes).
    unsigned s3m = 0u - ((S >> 3) & 1u);
    unsigned V0 = (0xF0u ^ s3m) & 0xFFu;
    const unsigned V1 = 0x3Cu, V2 = 0x66u;

    unsigned B[3];
#pragma unroll
    for (int d = 0; d < 3; ++d) {
        unsigned cd = 0u - ((G[d] >> 11) & 1u);
        unsigned a0 = (0u - ((G[d] >> 8) & 1u)) ^ cd;
        unsigned a1 = (0u - ((G[d] >> 9) & 1u)) ^ cd;
        unsigned a2 = (0u - ((G[d] >> 10) & 1u)) ^ cd;
        B[d] = ((a0 & V0) ^ (a1 & V1) ^ (a2 & V2) ^ cd) & 0xFFu;
    }

    unsigned baseflat = ((G[0] & 0xFEu) << 16) | ((G[1] & 0xFEu) << 8)
                      | (G[2] & 0xFEu);

    // Load the 2x2x2 cube as 4 z-pair float2s (8B aligned: baseflat even).
    const float2* xp = (const float2*)(x + baseflat);
    float2 p00 = xp[0];              // i=0 (x), j=0 (y)
    float2 p01 = xp[128];            // j=1 : +256 floats
    float2 p10 = xp[32768];          // i=1 : +65536 floats
    float2 p11 = xp[32768 + 128];

    float out8[8];
#pragma unroll
    for (int r = 0; r < 8; ++r) {
        unsigned f0 = (B[0] >> r) & 1u;   // x bit
        unsigned f1 = (B[1] >> r) & 1u;   // y bit
        unsigned f2 = (B[2] >> r) & 1u;   // z bit
        float2 t0 = f1 ? p01 : p00;
        float2 t1 = f1 ? p11 : p10;
        float2 t  = f0 ? t1 : t0;
        out8[r] = f2 ? t.y : t.x;
    }
    float4* o4 = (float4*)(out + S);
    o4[0] = make_float4(out8[0], out8[1], out8[2], out8[3]);
    o4[1] = make_float4(out8[4], out8[5], out8[6], out8[7]);
}

extern "C" void kernel_launch(void* const* d_in, const int* in_sizes, int n_in,
                              void* d_out, int out_size, void* d_ws, size_t ws_size,
                              hipStream_t stream) {
    const float* x = (const float*)d_in[0];
    float* out = (float*)d_out;
    unsigned n = (unsigned)out_size;               // 16777216
    unsigned ngroups = n >> 3;                     // 2097152
    unsigned blocks = (ngroups + 255u) / 256u;     // 8192 (divisible by 8)
    hilbert_gather8v_kernel<<<blocks, 256, 0, stream>>>(x, out, ngroups);
}